// Round 8
// baseline (643.747 us; speedup 1.0000x reference)
//
#include <hip/hip_runtime.h>
#include <math.h>

typedef __attribute__((ext_vector_type(4))) float f32x4;
typedef __attribute__((ext_vector_type(8))) __bf16 bf16x8;
typedef __attribute__((ext_vector_type(8))) short short8;

#define DEV __device__ __forceinline__

DEV short f2bfs(float f) {
    unsigned u = __builtin_bit_cast(unsigned, f);
    unsigned r = (u + 0x7FFFu + ((u >> 16) & 1u)) >> 16;   // RNE
    return (short)r;
}

DEV f32x4 mfma16(bf16x8 a, bf16x8 b, f32x4 c) {
    return __builtin_amdgcn_mfma_f32_16x16x32_bf16(a, b, c, 0, 0, 0);
}

DEV void gload_lds16(const void* g, void* l) {
    __builtin_amdgcn_global_load_lds((const __attribute__((address_space(1))) void*)g,
                                     (__attribute__((address_space(3))) void*)l, 16, 0, 0);
}

// ---------------------------------------------------------------------------
// Weight convert+transpose: Win f32 [Kd,Nd] -> Wout bf16 [Nd,Kd].
// 64x64 tile / 256 threads: float4 loads, short4 stores.
// ---------------------------------------------------------------------------
__global__ __launch_bounds__(256) void wtrans(const float* __restrict__ Win,
                                              short* __restrict__ Wout,
                                              int Kd, int Nd) {
    __shared__ float Tt[64][65];
    const int tx = threadIdx.x & 15, ty = threadIdx.x >> 4;   // 16x16 threads
    const int k0 = blockIdx.y * 64, n0 = blockIdx.x * 64;
#pragma unroll
    for (int rr = 0; rr < 4; ++rr) {
        int k = ty + rr * 16;
        float4 v = *(const float4*)&Win[(size_t)(k0 + k) * Nd + n0 + tx * 4];
        Tt[k][tx * 4 + 0] = v.x; Tt[k][tx * 4 + 1] = v.y;
        Tt[k][tx * 4 + 2] = v.z; Tt[k][tx * 4 + 3] = v.w;
    }
    __syncthreads();
#pragma unroll
    for (int rr = 0; rr < 4; ++rr) {
        int n = ty + rr * 16;
        short4 o;
        o.x = f2bfs(Tt[tx * 4 + 0][n]);
        o.y = f2bfs(Tt[tx * 4 + 1][n]);
        o.z = f2bfs(Tt[tx * 4 + 2][n]);
        o.w = f2bfs(Tt[tx * 4 + 3][n]);
        *(short4*)&Wout[(size_t)(n0 + n) * Kd + k0 + tx * 4] = o;
    }
}

struct WPtrs { const float* p[8]; };

// 8 x (1024x1024) weights -> contiguous bf16 [8][1024][1024] transposed
__global__ __launch_bounds__(256) void wtrans8(WPtrs wp, short* __restrict__ out) {
    const float* __restrict__ Win = wp.p[blockIdx.z];
    short* __restrict__ Wout = out + (size_t)blockIdx.z * (1024 * 1024);
    __shared__ float Tt[64][65];
    const int tx = threadIdx.x & 15, ty = threadIdx.x >> 4;
    const int k0 = blockIdx.y * 64, n0 = blockIdx.x * 64;
#pragma unroll
    for (int rr = 0; rr < 4; ++rr) {
        int k = ty + rr * 16;
        float4 v = *(const float4*)&Win[(size_t)(k0 + k) * 1024 + n0 + tx * 4];
        Tt[k][tx * 4 + 0] = v.x; Tt[k][tx * 4 + 1] = v.y;
        Tt[k][tx * 4 + 2] = v.z; Tt[k][tx * 4 + 3] = v.w;
    }
    __syncthreads();
#pragma unroll
    for (int rr = 0; rr < 4; ++rr) {
        int n = ty + rr * 16;
        short4 o;
        o.x = f2bfs(Tt[tx * 4 + 0][n]);
        o.y = f2bfs(Tt[tx * 4 + 1][n]);
        o.z = f2bfs(Tt[tx * 4 + 2][n]);
        o.w = f2bfs(Tt[tx * 4 + 3][n]);
        *(short4*)&Wout[(size_t)(n0 + n) * 1024 + k0 + tx * 4] = o;
    }
}

// f32 -> bf16 elementwise (8 per thread: 2x float4 -> short8)
__global__ __launch_bounds__(256) void conv_bf16(const float* __restrict__ X,
                                                 short* __restrict__ Y, int n8) {
    int i = blockIdx.x * 256 + threadIdx.x;
    if (i < n8) {
        float4 a = ((const float4*)X)[i * 2];
        float4 b = ((const float4*)X)[i * 2 + 1];
        short8 o;
        o[0] = f2bfs(a.x); o[1] = f2bfs(a.y); o[2] = f2bfs(a.z); o[3] = f2bfs(a.w);
        o[4] = f2bfs(b.x); o[5] = f2bfs(b.y); o[6] = f2bfs(b.z); o[7] = f2bfs(b.w);
        ((short8*)Y)[i] = o;
    }
}

// ---------------------------------------------------------------------------
// GEMM v12: A bf16 [M,Ks] rm, BT bf16 [N,Ks] rm. Tile BM x BN, BK in {32,64},
// A double-buffered in LDS via global_load_lds, one __syncthreads per K-iter.
// BDIR (skinny-N 64² GEMMs): B fragments read DIRECTLY from global (L2-hot,
//   B <= 8.4 MB) — per-lane 16B contiguous, rg-groups form 64B segments/row.
//   Removes B from LDS staging + barrier drain, halves LDS reads per MFMA,
//   LDS 16 KB -> 6 blocks/CU. Rationale: R0-R6 ledger shows every staged
//   config (64², 128x64, 128², split-K, deep-pipe, either stripe swizzle)
//   converges at ~60µs / 22% MfmaUtil on ffn_w2 with near-ideal FETCH —
//   the common factor was the B-through-LDS critical path.
// SWZ: 0 = linear, 1 = y-stripe per XCD (A-slice+B working set; correct
//   choice since A >> B), 2 = x-stripe (REFUTED R7: A streams per-XCD,
//   FETCH 49->206 MB).
// EPI 0: f32 [M,N] + bias (o0,b0)
// EPI 1: QKV fused: seg0->Q head *0.125 (o0,b0), seg1->K head(o1,b1),
//        seg2->V^T [bh][64][1024](o2,b2). Also single Q (N=1024).
// EPI 2: GELU bf16 [M,N] (o0,b0)
// EPI 3: KV fused (N=2048): seg0->K head(o0,b0), seg1->V^T(o1,b1)
// ---------------------------------------------------------------------------
template <int BM, int BN, int BK, int EPI, int SWZ, bool BDIR = false>
__global__ __launch_bounds__(256, (BM == 64 && BN == 64) ? 6 : 1)
void gemm_bt(const short* __restrict__ A,
             const short* __restrict__ BT,
             const float* __restrict__ b0,
             const float* __restrict__ b1,
             const float* __restrict__ b2,
             void* __restrict__ o0,
             void* __restrict__ o1,
             void* __restrict__ o2,
             int M, int N, int K, int Ks) {
    constexpr int IM = BM / 32, JN = BN / 32;
    constexpr int KH = BK / 32;            // k-halves per tile
    constexpr int AL = (BM * 64) / 4096;   // A loads per thread per k-half
    constexpr int BL = (BN * 64) / 4096;   // B loads per thread per k-half
    __shared__ __align__(16) short As[2][BM * BK];
    __shared__ __align__(16) short Bs[2][BDIR ? 8 : BN * BK];
    const int tid = threadIdx.x, lane = tid & 63, w = tid >> 6;

    int bx, by, bz;
    if (SWZ == 1) {          // y-stripe per XCD
        int gx = gridDim.x, gy = gridDim.y;
        int G = gx * gy * gridDim.z;
        int fid = blockIdx.x + gx * (blockIdx.y + gy * blockIdx.z);
        int nf = (fid & 7) * (G >> 3) + (fid >> 3);
        bx = nf % gx;
        int t = nf / gx;
        by = t % gy;
        bz = t / gy;
    } else {
        bx = blockIdx.x; by = blockIdx.y; bz = blockIdx.z;
    }

    const int m0 = by * BM, n0 = bx * BN;
    const int kz = bz * K;
    const int wm = (w & 1) * (BM / 2), wn = (w >> 1) * (BN / 2);
    const int rl = lane & 15, rg = lane >> 4;
    f32x4 acc[IM][JN] = {};
    const char* Ab = (const char*)A;
    const char* Bb = (const char*)BT;
    const int nk = K / BK;

    auto stage = [&](int kt, int buf) {
#pragma unroll
        for (int h = 0; h < KH; ++h) {
#pragma unroll
            for (int r = 0; r < AL; ++r) {       // A k-half: BM rows x 64 B
                int lo = (tid + r * 256) * 16;
                int row = lo >> 6, cp = (lo >> 4) & 3, c = (cp - (row >> 1)) & 3;
                gload_lds16(Ab + ((size_t)(m0 + row) * Ks + kz + kt * BK + h * 32 + c * 8) * 2,
                            (char*)As[buf] + h * (BM * 64) + lo);
            }
            if constexpr (!BDIR) {
#pragma unroll
                for (int r = 0; r < BL; ++r) {   // B k-half: BN rows x 64 B
                    int lo = (tid + r * 256) * 16;
                    int row = lo >> 6, cp = (lo >> 4) & 3, c = (cp - (row >> 1)) & 3;
                    gload_lds16(Bb + ((size_t)(n0 + row) * Ks + kz + kt * BK + h * 32 + c * 8) * 2,
                                (char*)Bs[buf] + h * (BN * 64) + lo);
                }
            }
        }
    };

    stage(0, 0);
    for (int kt = 0; kt < nk; ++kt) {
        const int buf = kt & 1;
        __syncthreads();                 // drains tile-kt loads (covered by kt-1)
        if (kt + 1 < nk) stage(kt + 1, buf ^ 1);
        bf16x8 af[KH][IM], bfr[KH][JN];
#pragma unroll
        for (int h = 0; h < KH; ++h) {
#pragma unroll
            for (int i = 0; i < IM; i++) {
                int row = wm + i * 16 + rl;
                af[h][i] = *(const bf16x8*)(As[buf] + h * (BM * 32) + row * 32 +
                                            ((rg + (row >> 1)) & 3) * 8);
            }
#pragma unroll
            for (int j = 0; j < JN; j++) {
                int row = wn + j * 16 + rl;
                if constexpr (BDIR) {
                    bfr[h][j] = *(const bf16x8*)(Bb + ((size_t)(n0 + row) * Ks + kz +
                                                       kt * BK + h * 32 + rg * 8) * 2);
                } else {
                    bfr[h][j] = *(const bf16x8*)(Bs[buf] + h * (BN * 32) + row * 32 +
                                                 ((rg + (row >> 1)) & 3) * 8);
                }
            }
        }
#pragma unroll
        for (int h = 0; h < KH; ++h)
#pragma unroll
            for (int i = 0; i < IM; i++)
#pragma unroll
                for (int j = 0; j < JN; j++)
                    acc[i][j] = mfma16(af[h][i], bfr[h][j], acc[i][j]);
    }

    float* o0z = (float*)o0 + (size_t)bz * M * N;
#pragma unroll
    for (int i = 0; i < IM; i++) {
        int gm0 = m0 + wm + i * 16 + rg * 4;
#pragma unroll
        for (int j = 0; j < JN; j++) {
            int gn = n0 + wn + j * 16 + rl;
            if (EPI == 0) {
                float bv = bz == 0 ? b0[gn] : 0.0f;
#pragma unroll
                for (int r = 0; r < 4; r++)
                    o0z[(size_t)(gm0 + r) * N + gn] = acc[i][j][r] + bv;
            } else if (EPI == 2) {
                float bv = b0[gn];
#pragma unroll
                for (int r = 0; r < 4; r++) {
                    float x = acc[i][j][r] + bv;
                    // gelu(x) ~= x * sigmoid(1.59577(x + 0.044715 x^3))
                    float z = 1.59576912f * x + 0.07135481f * x * x * x;
                    float g = x / (1.0f + __expf(-z));
                    ((short*)o0)[(size_t)(gm0 + r) * N + gn] = f2bfs(g);
                }
            } else {  // EPI 1 / 3: head or V^T layouts
                int seg = gn >> 10, n1 = gn & 1023, h = n1 >> 6, d = n1 & 63;
                int b = gm0 >> 10, t0 = gm0 & 1023;
                bool isV = (EPI == 1) ? (seg == 2) : (seg == 1);
                const float* bp = (EPI == 1) ? (seg == 0 ? b0 : (seg == 1 ? b1 : b2))
                                             : (seg == 0 ? b0 : b1);
                float bv = bp[n1];
                float qs = (EPI == 1 && seg == 0) ? 0.125f : 1.0f;  // 1/sqrt(dk)
                if (!isV) {
                    short* hp = (short*)((EPI == 1) ? (seg == 0 ? o0 : o1) : o0);
                    size_t base = ((size_t)(b * 16 + h) * 1024 + t0) * 64 + d;
#pragma unroll
                    for (int r = 0; r < 4; r++)
                        hp[base + (size_t)r * 64] = f2bfs((acc[i][j][r] + bv) * qs);
                } else {
                    short* vp = (short*)((EPI == 1) ? o2 : o1);
                    short4 pk;
                    pk.x = f2bfs(acc[i][j][0] + bv);
                    pk.y = f2bfs(acc[i][j][1] + bv);
                    pk.z = f2bfs(acc[i][j][2] + bv);
                    pk.w = f2bfs(acc[i][j][3] + bv);
                    *(short4*)(vp + ((size_t)(b * 16 + h) * 64 + d) * 1024 + t0) = pk;
                }
            }
        }
    }
}

// ---------------------------------------------------------------------------
// Flash attention v4: LDS double-buffered K/V staging via global_load_lds,
// one barrier per 64-key tile (loads covered by a full tile of compute).
// Transposed scores (S^T = K*Q^T), no cross-lane reductions, l via ones-MFMA.
// Q pre-scaled by 1/8. Block = (b,h,64 Q rows), 4 waves x 16 rows.
// CAUSAL: block order reversed (heavy Q-tiles dispatch first) so the tail of
// execution is the light blocks, not the 16-tile ones.
// ---------------------------------------------------------------------------
template <bool CAUSAL>
__global__ __launch_bounds__(256, 3) void attn4(const short* __restrict__ Qh,
                                                const short* __restrict__ Kh,
                                                const short* __restrict__ VTh,
                                                short* __restrict__ Out, int TKn) {
    __shared__ __align__(16) short Ks[2][64 * 64];    // [key][d], swizzled segs
    __shared__ __align__(16) short Vts[2][64 * 64];   // [d][key], swizzled segs
    __shared__ __align__(16) short Ps[4][16 * 72 + 8];
    const int tid = threadIdx.x, lane = tid & 63, w = tid >> 6;
    const int rl = lane & 15, rg = lane >> 4;
    const int bh = blockIdx.y, b = bh >> 4, h = bh & 15;
    const int qb = CAUSAL ? (gridDim.x - 1 - blockIdx.x) : blockIdx.x;
    const int q0 = qb * 64;
    const short* Qp = Qh + (size_t)bh * 1024 * 64;
    const char* Kp = (const char*)(Kh + (size_t)bh * (size_t)TKn * 64);
    const char* Vp = (const char*)(VTh + (size_t)bh * (size_t)TKn * 64);

    const int qrow = q0 + w * 16 + rl;
    const bf16x8 qf0 = *(const bf16x8*)(Qp + (size_t)qrow * 64 + rg * 8);
    const bf16x8 qf1 = *(const bf16x8*)(Qp + (size_t)qrow * 64 + 32 + rg * 8);

    bf16x8 onesf;
#pragma unroll
    for (int i = 0; i < 8; ++i) onesf[i] = (__bf16)1.0f;

    f32x4 o[4] = {};
    f32x4 lacc = {};

    short* Pw = &Ps[w][0];
    const int nkt = CAUSAL ? qb + 1 : (TKn >> 6);

    auto stage = [&](int kt, int buf) {
#pragma unroll
        for (int r = 0; r < 2; ++r) {
            int lo = (w * 2 + r) * 1024 + lane * 16;   // byte offset in tile
            int row = lo >> 7, cp = (lo >> 4) & 7, c = (cp - row) & 7;
            gload_lds16(Kp + ((size_t)(kt * 64 + row) * 64 + c * 8) * 2,
                        (char*)Ks[buf] + lo);
            gload_lds16(Vp + ((size_t)row * TKn + kt * 64 + c * 8) * 2,
                        (char*)Vts[buf] + lo);
        }
    };

    stage(0, 0);
    for (int kt = 0; kt < nkt; ++kt) {
        const int buf = kt & 1;
        __syncthreads();                    // drains this tile's loads (covered)
        if (kt + 1 < nkt) stage(kt + 1, buf ^ 1);

        // --- S^T = K * Q^T (A = K frag: m = key, B = Q frag: n = q) ---
        const short* KsB = Ks[buf];
        f32x4 s[4];
#pragma unroll
        for (int ch = 0; ch < 4; ++ch) {
            int row = ch * 16 + rl;
            bf16x8 k0 = *(const bf16x8*)(KsB + row * 64 + ((rg + row) & 7) * 8);
            bf16x8 k1 = *(const bf16x8*)(KsB + row * 64 + ((rg + 4 + row) & 7) * 8);
            f32x4 z = {};
            z = mfma16(k0, qf0, z);
            z = mfma16(k1, qf1, z);
            s[ch] = z;
        }
        // --- exp + causal mask (last tile only) + P^T pack to LDS ---
        const bool domask = CAUSAL && (kt == nkt - 1);
#pragma unroll
        for (int ch = 0; ch < 4; ++ch) {
            float p[4];
#pragma unroll
            for (int r = 0; r < 4; ++r) {
                float e = __expf(s[ch][r]);
                if (domask) {
                    int key = kt * 64 + ch * 16 + rg * 4 + r;
                    if (key > qrow) e = 0.0f;
                }
                p[r] = e;
            }
            unsigned d0 = (__builtin_bit_cast(unsigned, p[1]) & 0xFFFF0000u) |
                          (__builtin_bit_cast(unsigned, p[0]) >> 16);
            unsigned d1 = (__builtin_bit_cast(unsigned, p[3]) & 0xFFFF0000u) |
                          (__builtin_bit_cast(unsigned, p[2]) >> 16);
            uint2 dv; dv.x = d0; dv.y = d1;
            *(uint2*)(Pw + rl * 72 + ch * 16 + rg * 4) = dv;
        }
        // --- P A-frags + row-sum + PV ---
        bf16x8 pa0 = *(const bf16x8*)(Pw + rl * 72 + rg * 8);
        bf16x8 pa1 = *(const bf16x8*)(Pw + rl * 72 + 32 + rg * 8);
        lacc = mfma16(pa0, onesf, lacc);
        lacc = mfma16(pa1, onesf, lacc);
        const short* VsB = Vts[buf];
#pragma unroll
        for (int j = 0; j < 4; ++j) {
            int row = j * 16 + rl;
            bf16x8 v0 = *(const bf16x8*)(VsB + row * 64 + ((rg + row) & 7) * 8);
            bf16x8 v1 = *(const bf16x8*)(VsB + row * 64 + ((rg + 4 + row) & 7) * 8);
            o[j] = mfma16(pa0, v0, o[j]);
            o[j] = mfma16(pa1, v1, o[j]);
        }
    }

    float inv[4];
#pragma unroll
    for (int r = 0; r < 4; r++) inv[r] = 1.0f / lacc[r];
#pragma unroll
    for (int j = 0; j < 4; j++) {
#pragma unroll
        for (int r = 0; r < 4; r++) {
            int row = q0 + w * 16 + rg * 4 + r;
            int col = h * 64 + j * 16 + rl;
            Out[((size_t)b * 1024 + row) * 1024 + col] = f2bfs(o[j][r] * inv[r]);
        }
    }
}

// ---------------------------------------------------------------------------
// Fused residual add (+ optional second partial R2) + LayerNorm over C=1024.
// Writes f32 (+optional bf16).
// ---------------------------------------------------------------------------
__global__ __launch_bounds__(256) void ln_fused(const float* __restrict__ X,
                                                const float* __restrict__ R,
                                                const float* __restrict__ R2,
                                                const float* __restrict__ gam,
                                                const float* __restrict__ bet,
                                                float* __restrict__ Yf,
                                                short* __restrict__ Yb) {
    const int row = blockIdx.x, tid = threadIdx.x;
    const int lane = tid & 63, w = tid >> 6;
    float4 xv = ((const float4*)(X + (size_t)row * 1024))[tid];
    float4 rv = ((const float4*)(R + (size_t)row * 1024))[tid];
    float v0 = xv.x + rv.x, v1 = xv.y + rv.y, v2 = xv.z + rv.z, v3 = xv.w + rv.w;
    if (R2) {
        float4 r2 = ((const float4*)(R2 + (size_t)row * 1024))[tid];
        v0 += r2.x; v1 += r2.y; v2 += r2.z; v3 += r2.w;
    }
    float s = v0 + v1 + v2 + v3;
    float ss = v0 * v0 + v1 * v1 + v2 * v2 + v3 * v3;
#pragma unroll
    for (int off = 1; off < 64; off <<= 1) {
        s += __shfl_xor(s, off);
        ss += __shfl_xor(ss, off);
    }
    __shared__ float sred[4], ssred[4];
    if (lane == 0) { sred[w] = s; ssred[w] = ss; }
    __syncthreads();
    s = sred[0] + sred[1] + sred[2] + sred[3];
    ss = ssred[0] + ssred[1] + ssred[2] + ssred[3];
    float mu = s * (1.0f / 1024.0f);
    float var = ss * (1.0f / 1024.0f) - mu * mu;
    float rsq = rsqrtf(var + 1e-12f);
    float4 gv = ((const float4*)gam)[tid];
    float4 bv = ((const float4*)bet)[tid];
    float y0 = (v0 - mu) * rsq * gv.x + bv.x;
    float y1 = (v1 - mu) * rsq * gv.y + bv.y;
    float y2 = (v2 - mu) * rsq * gv.z + bv.z;
    float y3 = (v3 - mu) * rsq * gv.w + bv.w;
    float4 yo = {y0, y1, y2, y3};
    ((float4*)(Yf + (size_t)row * 1024))[tid] = yo;
    if (Yb) {
        short4 ob;
        ob.x = f2bfs(y0); ob.y = f2bfs(y1); ob.z = f2bfs(y2); ob.w = f2bfs(y3);
        ((short4*)(Yb + (size_t)row * 1024))[tid] = ob;
    }
}

// ---------------------------------------------------------------------------
extern "C" void kernel_launch(void* const* d_in, const int* in_sizes, int n_in,
                              void* d_out, int out_size, void* d_ws, size_t ws_size,
                              hipStream_t stream) {
    const float* src = (const float*)d_in[0];
    const float* dst = (const float*)d_in[1];
    // d_in[2]=src_mask (all valid), d_in[3]=dst_mask (causal) — structurally fixed
    const float* sa_wq = (const float*)d_in[4];
    const float* sa_wk = (const float*)d_in[5];
    const float* sa_wv = (const float*)d_in[6];
    const float* sa_wo = (const float*)d_in[7];
    const float* sa_bq = (const float*)d_in[8];
    const float* sa_bk = (const float*)d_in[9];
    const float* sa_bv = (const float*)d_in[10];
    const float* sa_bo = (const float*)d_in[11];
    const float* ca_wq = (const float*)d_in[12];
    const float* ca_wk = (const float*)d_in[13];
    const float* ca_wv = (const float*)d_in[14];
    const float* ca_wo = (const float*)d_in[15];
    const float* ca_bq = (const float*)d_in[16];
    const float* ca_bk = (const float*)d_in[17];
    const float* ca_bv = (const float*)d_in[18];
    const float* ca_bo = (const float*)d_in[19];
    const float* ffn_w1 = (const float*)d_in[20];
    const float* ffn_b1 = (const float*)d_in[21];
    const float* ffn_w2 = (const float*)d_in[22];
    const float* ffn_b2 = (const float*)d_in[23];
    const float* ln1g = (const float*)d_in[24];
    const float* ln1b = (const float*)d_in[25];
    const float* ln2g = (const float*)d_in[26];
    const float* ln2b = (const float*)d_in[27];
    const float* ln3g = (const float*)d_in[28];
    const float* ln3b = (const float*)d_in[29];

    char* ws = (char*)d_ws;
    size_t off = 0;
    auto alloc = [&](size_t n) { size_t o = off; off = (off + n + 255) & ~(size_t)255; return o; };

    const size_t szW = (size_t)1024 * 1024 * 2;      // 2 MB bf16 1024x1024
    short* wT = (short*)(ws + alloc(8 * szW));       // 8 transposed attn weights
    short* w1T = (short*)(ws + alloc((size_t)4096 * 1024 * 2));
    short* w2T = (short*)(ws + alloc((size_t)1024 * 4096 * 2));
    const size_t szAct2 = (size_t)4096 * 1024 * 2;   // 8 MB bf16 activations
    const size_t szAct4 = (size_t)4096 * 1024 * 4;   // 16 MB f32 activations
    short* dstb = (short*)(ws + alloc(szAct2));
    short* srcb = (short*)(ws + alloc(szAct2));
    short* Qh = (short*)(ws + alloc(szAct2));
    short* Kh = (short*)(ws + alloc(szAct2));
    short* VTh = (short*)(ws + alloc(szAct2));
    short* attnb = (short*)(ws + alloc(szAct2));
    float* tmp = (float*)(ws + alloc(szAct4));       // single f32 GEMM output
    float* y1f = (float*)(ws + alloc(szAct4));
    short* y1b = (short*)(ws + alloc(szAct2));
    float* y2f = (float*)(ws + alloc(szAct4));
    short* y2b = (short*)(ws + alloc(szAct2));
    short* ffnh = (short*)(ws + alloc((size_t)4096 * 4096 * 2));

    // transposed-weight views (order matches WPtrs below)
    short* sa_wqkvT = wT;                 // rows 0..3071 = wq^T, wk^T, wv^T
    short* sa_woT = wT + 3 * (size_t)1048576;
    short* ca_wqT = wT + 4 * (size_t)1048576;
    short* ca_wkvT = wT + 5 * (size_t)1048576;  // rows 0..2047 = wk^T, wv^T
    short* ca_woT = wT + 7 * (size_t)1048576;

    dim3 blk(256);

    // weight prep
    WPtrs wp = {{sa_wq, sa_wk, sa_wv, sa_wo, ca_wq, ca_wk, ca_wv, ca_wo}};
    wtrans8<<<dim3(16, 16, 8), blk, 0, stream>>>(wp, wT);
    wtrans<<<dim3(64, 16), blk, 0, stream>>>(ffn_w1, w1T, 1024, 4096);
    wtrans<<<dim3(16, 64), blk, 0, stream>>>(ffn_w2, w2T, 4096, 1024);
    conv_bf16<<<2048, blk, 0, stream>>>(dst, dstb, 524288);
    conv_bf16<<<2048, blk, 0, stream>>>(src, srcb, 524288);

    // ---- self-attention ----
    gemm_bt<128, 128, 32, 1, 0><<<dim3(24, 32), blk, 0, stream>>>(
        dstb, sa_wqkvT, sa_bq, sa_bk, sa_bv, Qh, Kh, VTh, 4096, 3072, 1024, 1024);
    attn4<true><<<dim3(16, 64), blk, 0, stream>>>(Qh, Kh, VTh, attnb, 1024);
    gemm_bt<64, 64, 64, 0, 1, true><<<dim3(16, 64), blk, 0, stream>>>(
        attnb, sa_woT, sa_bo, nullptr, nullptr, tmp, nullptr, nullptr, 4096, 1024, 1024, 1024);
    ln_fused<<<4096, blk, 0, stream>>>(dst, tmp, nullptr, ln1g, ln1b, y1f, y1b);

    // ---- cross-attention ----
    gemm_bt<64, 64, 64, 1, 1, true><<<dim3(16, 64), blk, 0, stream>>>(
        y1b, ca_wqT, ca_bq, nullptr, nullptr, Qh, nullptr, nullptr, 4096, 1024, 1024, 1024);
    gemm_bt<128, 128, 32, 3, 0><<<dim3(16, 32), blk, 0, stream>>>(
        srcb, ca_wkvT, ca_bk, ca_bv, nullptr, Kh, VTh, nullptr, 4096, 2048, 1024, 1024);
    attn4<false><<<dim3(16, 64), blk, 0, stream>>>(Qh, Kh, VTh, attnb, 1024);
    gemm_bt<64, 64, 64, 0, 1, true><<<dim3(16, 64), blk, 0, stream>>>(
        attnb, ca_woT, ca_bo, nullptr, nullptr, tmp, nullptr, nullptr, 4096, 1024, 1024, 1024);
    ln_fused<<<4096, blk, 0, stream>>>(y1f, tmp, nullptr, ln2g, ln2b, y2f, y2b);

    // ---- FFN ----
    gemm_bt<128, 128, 32, 2, 0><<<dim3(32, 32), blk, 0, stream>>>(
        y2b, w1T, ffn_b1, nullptr, nullptr, ffnh, nullptr, nullptr, 4096, 4096, 1024, 1024);
    gemm_bt<64, 64, 64, 0, 1, true><<<dim3(16, 64), blk, 0, stream>>>(
        ffnh, w2T, ffn_b2, nullptr, nullptr, tmp, nullptr, nullptr, 4096, 1024, 4096, 4096);
    ln_fused<<<4096, blk, 0, stream>>>(y2f, tmp, nullptr, ln3g, ln3b, (float*)d_out, nullptr);

    (void)in_sizes; (void)n_in; (void)out_size; (void)ws_size;
}

// Round 11
// 513.456 us; speedup vs baseline: 1.2538x; 1.2538x over previous
//
#include <hip/hip_runtime.h>
#include <math.h>

// build r10: identical semantics to r9 submission; resubmitted after two
// infra-side container failures (source components all previously HW-verified:
// GEMM config == R2 winner; vectorized prep == R4; reversed causal attn == R8).

typedef __attribute__((ext_vector_type(4))) float f32x4;
typedef __attribute__((ext_vector_type(8))) __bf16 bf16x8;
typedef __attribute__((ext_vector_type(8))) short short8;

#define DEV __device__ __forceinline__

DEV short f2bfs(float f) {
    unsigned u = __builtin_bit_cast(unsigned, f);
    unsigned r = (u + 0x7FFFu + ((u >> 16) & 1u)) >> 16;   // RNE
    return (short)r;
}

DEV f32x4 mfma16(bf16x8 a, bf16x8 b, f32x4 c) {
    return __builtin_amdgcn_mfma_f32_16x16x32_bf16(a, b, c, 0, 0, 0);
}

DEV void gload_lds16(const void* g, void* l) {
    __builtin_amdgcn_global_load_lds((const __attribute__((address_space(1))) void*)g,
                                     (__attribute__((address_space(3))) void*)l, 16, 0, 0);
}

// ---------------------------------------------------------------------------
// Weight convert+transpose: Win f32 [Kd,Nd] -> Wout bf16 [Nd,Kd].
// 64x64 tile / 256 threads: float4 loads, short4 stores.
// ---------------------------------------------------------------------------
__global__ __launch_bounds__(256) void wtrans(const float* __restrict__ Win,
                                              short* __restrict__ Wout,
                                              int Kd, int Nd) {
    __shared__ float Tt[64][65];
    const int tx = threadIdx.x & 15, ty = threadIdx.x >> 4;   // 16x16 threads
    const int k0 = blockIdx.y * 64, n0 = blockIdx.x * 64;
#pragma unroll
    for (int rr = 0; rr < 4; ++rr) {
        int k = ty + rr * 16;
        float4 v = *(const float4*)&Win[(size_t)(k0 + k) * Nd + n0 + tx * 4];
        Tt[k][tx * 4 + 0] = v.x; Tt[k][tx * 4 + 1] = v.y;
        Tt[k][tx * 4 + 2] = v.z; Tt[k][tx * 4 + 3] = v.w;
    }
    __syncthreads();
#pragma unroll
    for (int rr = 0; rr < 4; ++rr) {
        int n = ty + rr * 16;
        short4 o;
        o.x = f2bfs(Tt[tx * 4 + 0][n]);
        o.y = f2bfs(Tt[tx * 4 + 1][n]);
        o.z = f2bfs(Tt[tx * 4 + 2][n]);
        o.w = f2bfs(Tt[tx * 4 + 3][n]);
        *(short4*)&Wout[(size_t)(n0 + n) * Kd + k0 + tx * 4] = o;
    }
}

struct WPtrs { const float* p[8]; };

// 8 x (1024x1024) weights -> contiguous bf16 [8][1024][1024] transposed
__global__ __launch_bounds__(256) void wtrans8(WPtrs wp, short* __restrict__ out) {
    const float* __restrict__ Win = wp.p[blockIdx.z];
    short* __restrict__ Wout = out + (size_t)blockIdx.z * (1024 * 1024);
    __shared__ float Tt[64][65];
    const int tx = threadIdx.x & 15, ty = threadIdx.x >> 4;
    const int k0 = blockIdx.y * 64, n0 = blockIdx.x * 64;
#pragma unroll
    for (int rr = 0; rr < 4; ++rr) {
        int k = ty + rr * 16;
        float4 v = *(const float4*)&Win[(size_t)(k0 + k) * 1024 + n0 + tx * 4];
        Tt[k][tx * 4 + 0] = v.x; Tt[k][tx * 4 + 1] = v.y;
        Tt[k][tx * 4 + 2] = v.z; Tt[k][tx * 4 + 3] = v.w;
    }
    __syncthreads();
#pragma unroll
    for (int rr = 0; rr < 4; ++rr) {
        int n = ty + rr * 16;
        short4 o;
        o.x = f2bfs(Tt[tx * 4 + 0][n]);
        o.y = f2bfs(Tt[tx * 4 + 1][n]);
        o.z = f2bfs(Tt[tx * 4 + 2][n]);
        o.w = f2bfs(Tt[tx * 4 + 3][n]);
        *(short4*)&Wout[(size_t)(n0 + n) * 1024 + k0 + tx * 4] = o;
    }
}

// f32 -> bf16 elementwise (8 per thread: 2x float4 -> short8)
__global__ __launch_bounds__(256) void conv_bf16(const float* __restrict__ X,
                                                 short* __restrict__ Y, int n8) {
    int i = blockIdx.x * 256 + threadIdx.x;
    if (i < n8) {
        float4 a = ((const float4*)X)[i * 2];
        float4 b = ((const float4*)X)[i * 2 + 1];
        short8 o;
        o[0] = f2bfs(a.x); o[1] = f2bfs(a.y); o[2] = f2bfs(a.z); o[3] = f2bfs(a.w);
        o[4] = f2bfs(b.x); o[5] = f2bfs(b.y); o[6] = f2bfs(b.z); o[7] = f2bfs(b.w);
        ((short8*)Y)[i] = o;
    }
}

// ---------------------------------------------------------------------------
// GEMM (R2-winner config): A bf16 [M,Ks] rm, BT bf16 [N,Ks] rm.
// Tile BM x BN, BK in {32,64}, A+B double-buffered in LDS via global_load_lds,
// one __syncthreads per K-iter (m97 structure).
// Skinny-N (N=1024): 64²/BK64, 4 blk/CU, y-stripe swizzle. CLOSED LEDGER
//   (M=4096,N=1024,K=4096): 64² staged=59.6µs; 128x64=61.5; 64²+splitK=62;
//   128²@1blk+pipe=86; 128²+splitK4=59.4; x-stripe=78 (FETCH 4.2x);
//   B-direct=139.6 (scattered frag reads, exposed L2 latency). All
//   well-fetched configs converge ~60µs/22% MfmaUtil -> structural floor of
//   the 2-barrier-per-K-step schedule at this shape.
// SWZ: 0 = linear, 1 = y-stripe per XCD. (x-stripe REFUTED R7.)
// EPI 0: f32 [M,N] + bias (o0,b0)
// EPI 1: QKV fused: seg0->Q head *0.125 (o0,b0), seg1->K head(o1,b1),
//        seg2->V^T [bh][64][1024](o2,b2). Also single Q (N=1024).
// EPI 2: GELU bf16 [M,N] (o0,b0)
// EPI 3: KV fused (N=2048): seg0->K head(o0,b0), seg1->V^T(o1,b1)
// ---------------------------------------------------------------------------
template <int BM, int BN, int BK, int EPI, int SWZ>
__global__ __launch_bounds__(256, (BM == 64 && BN == 64) ? 4 : 1)
void gemm_bt(const short* __restrict__ A,
             const short* __restrict__ BT,
             const float* __restrict__ b0,
             const float* __restrict__ b1,
             const float* __restrict__ b2,
             void* __restrict__ o0,
             void* __restrict__ o1,
             void* __restrict__ o2,
             int M, int N, int K, int Ks) {
    constexpr int IM = BM / 32, JN = BN / 32;
    constexpr int KH = BK / 32;            // k-halves per tile
    constexpr int AL = (BM * 64) / 4096;   // A loads per thread per k-half
    constexpr int BL = (BN * 64) / 4096;   // B loads per thread per k-half
    __shared__ __align__(16) short As[2][BM * BK];
    __shared__ __align__(16) short Bs[2][BN * BK];
    const int tid = threadIdx.x, lane = tid & 63, w = tid >> 6;

    int bx, by, bz;
    if (SWZ == 1) {          // y-stripe per XCD
        int gx = gridDim.x, gy = gridDim.y;
        int G = gx * gy * gridDim.z;
        int fid = blockIdx.x + gx * (blockIdx.y + gy * blockIdx.z);
        int nf = (fid & 7) * (G >> 3) + (fid >> 3);
        bx = nf % gx;
        int t = nf / gx;
        by = t % gy;
        bz = t / gy;
    } else {
        bx = blockIdx.x; by = blockIdx.y; bz = blockIdx.z;
    }

    const int m0 = by * BM, n0 = bx * BN;
    const int kz = bz * K;
    const int wm = (w & 1) * (BM / 2), wn = (w >> 1) * (BN / 2);
    const int rl = lane & 15, rg = lane >> 4;
    f32x4 acc[IM][JN] = {};
    const char* Ab = (const char*)A;
    const char* Bb = (const char*)BT;
    const int nk = K / BK;

    auto stage = [&](int kt, int buf) {
#pragma unroll
        for (int h = 0; h < KH; ++h) {
#pragma unroll
            for (int r = 0; r < AL; ++r) {       // A k-half: BM rows x 64 B
                int lo = (tid + r * 256) * 16;
                int row = lo >> 6, cp = (lo >> 4) & 3, c = (cp - (row >> 1)) & 3;
                gload_lds16(Ab + ((size_t)(m0 + row) * Ks + kz + kt * BK + h * 32 + c * 8) * 2,
                            (char*)As[buf] + h * (BM * 64) + lo);
            }
#pragma unroll
            for (int r = 0; r < BL; ++r) {       // B k-half: BN rows x 64 B
                int lo = (tid + r * 256) * 16;
                int row = lo >> 6, cp = (lo >> 4) & 3, c = (cp - (row >> 1)) & 3;
                gload_lds16(Bb + ((size_t)(n0 + row) * Ks + kz + kt * BK + h * 32 + c * 8) * 2,
                            (char*)Bs[buf] + h * (BN * 64) + lo);
            }
        }
    };

    stage(0, 0);
    for (int kt = 0; kt < nk; ++kt) {
        const int buf = kt & 1;
        __syncthreads();                 // drains tile-kt loads (covered by kt-1)
        if (kt + 1 < nk) stage(kt + 1, buf ^ 1);
        bf16x8 af[KH][IM], bfr[KH][JN];
#pragma unroll
        for (int h = 0; h < KH; ++h) {
#pragma unroll
            for (int i = 0; i < IM; i++) {
                int row = wm + i * 16 + rl;
                af[h][i] = *(const bf16x8*)(As[buf] + h * (BM * 32) + row * 32 +
                                            ((rg + (row >> 1)) & 3) * 8);
            }
#pragma unroll
            for (int j = 0; j < JN; j++) {
                int row = wn + j * 16 + rl;
                bfr[h][j] = *(const bf16x8*)(Bs[buf] + h * (BN * 32) + row * 32 +
                                             ((rg + (row >> 1)) & 3) * 8);
            }
        }
#pragma unroll
        for (int h = 0; h < KH; ++h)
#pragma unroll
            for (int i = 0; i < IM; i++)
#pragma unroll
                for (int j = 0; j < JN; j++)
                    acc[i][j] = mfma16(af[h][i], bfr[h][j], acc[i][j]);
    }

    float* o0z = (float*)o0 + (size_t)bz * M * N;
#pragma unroll
    for (int i = 0; i < IM; i++) {
        int gm0 = m0 + wm + i * 16 + rg * 4;
#pragma unroll
        for (int j = 0; j < JN; j++) {
            int gn = n0 + wn + j * 16 + rl;
            if (EPI == 0) {
                float bv = bz == 0 ? b0[gn] : 0.0f;
#pragma unroll
                for (int r = 0; r < 4; r++)
                    o0z[(size_t)(gm0 + r) * N + gn] = acc[i][j][r] + bv;
            } else if (EPI == 2) {
                float bv = b0[gn];
#pragma unroll
                for (int r = 0; r < 4; r++) {
                    float x = acc[i][j][r] + bv;
                    // gelu(x) ~= x * sigmoid(1.59577(x + 0.044715 x^3))
                    float z = 1.59576912f * x + 0.07135481f * x * x * x;
                    float g = x / (1.0f + __expf(-z));
                    ((short*)o0)[(size_t)(gm0 + r) * N + gn] = f2bfs(g);
                }
            } else {  // EPI 1 / 3: head or V^T layouts
                int seg = gn >> 10, n1 = gn & 1023, h = n1 >> 6, d = n1 & 63;
                int b = gm0 >> 10, t0 = gm0 & 1023;
                bool isV = (EPI == 1) ? (seg == 2) : (seg == 1);
                const float* bp = (EPI == 1) ? (seg == 0 ? b0 : (seg == 1 ? b1 : b2))
                                             : (seg == 0 ? b0 : b1);
                float bv = bp[n1];
                float qs = (EPI == 1 && seg == 0) ? 0.125f : 1.0f;  // 1/sqrt(dk)
                if (!isV) {
                    short* hp = (short*)((EPI == 1) ? (seg == 0 ? o0 : o1) : o0);
                    size_t base = ((size_t)(b * 16 + h) * 1024 + t0) * 64 + d;
#pragma unroll
                    for (int r = 0; r < 4; r++)
                        hp[base + (size_t)r * 64] = f2bfs((acc[i][j][r] + bv) * qs);
                } else {
                    short* vp = (short*)((EPI == 1) ? o2 : o1);
                    short4 pk;
                    pk.x = f2bfs(acc[i][j][0] + bv);
                    pk.y = f2bfs(acc[i][j][1] + bv);
                    pk.z = f2bfs(acc[i][j][2] + bv);
                    pk.w = f2bfs(acc[i][j][3] + bv);
                    *(short4*)(vp + ((size_t)(b * 16 + h) * 64 + d) * 1024 + t0) = pk;
                }
            }
        }
    }
}

// ---------------------------------------------------------------------------
// Flash attention v4: LDS double-buffered K/V staging via global_load_lds,
// one barrier per 64-key tile (loads covered by a full tile of compute).
// Transposed scores (S^T = K*Q^T), no cross-lane reductions, l via ones-MFMA.
// Q pre-scaled by 1/8. Block = (b,h,64 Q rows), 4 waves x 16 rows.
// CAUSAL: block order reversed (heavy Q-tiles dispatch first) so the light
// 1-tile blocks fill the scheduling tail, not the 16-tile ones.
// ---------------------------------------------------------------------------
template <bool CAUSAL>
__global__ __launch_bounds__(256, 3) void attn4(const short* __restrict__ Qh,
                                                const short* __restrict__ Kh,
                                                const short* __restrict__ VTh,
                                                short* __restrict__ Out, int TKn) {
    __shared__ __align__(16) short Ks[2][64 * 64];    // [key][d], swizzled segs
    __shared__ __align__(16) short Vts[2][64 * 64];   // [d][key], swizzled segs
    __shared__ __align__(16) short Ps[4][16 * 72 + 8];
    const int tid = threadIdx.x, lane = tid & 63, w = tid >> 6;
    const int rl = lane & 15, rg = lane >> 4;
    const int bh = blockIdx.y, b = bh >> 4, h = bh & 15;
    const int qb = CAUSAL ? (gridDim.x - 1 - blockIdx.x) : blockIdx.x;
    const int q0 = qb * 64;
    const short* Qp = Qh + (size_t)bh * 1024 * 64;
    const char* Kp = (const char*)(Kh + (size_t)bh * (size_t)TKn * 64);
    const char* Vp = (const char*)(VTh + (size_t)bh * (size_t)TKn * 64);

    const int qrow = q0 + w * 16 + rl;
    const bf16x8 qf0 = *(const bf16x8*)(Qp + (size_t)qrow * 64 + rg * 8);
    const bf16x8 qf1 = *(const bf16x8*)(Qp + (size_t)qrow * 64 + 32 + rg * 8);

    bf16x8 onesf;
#pragma unroll
    for (int i = 0; i < 8; ++i) onesf[i] = (__bf16)1.0f;

    f32x4 o[4] = {};
    f32x4 lacc = {};

    short* Pw = &Ps[w][0];
    const int nkt = CAUSAL ? qb + 1 : (TKn >> 6);

    auto stage = [&](int kt, int buf) {
#pragma unroll
        for (int r = 0; r < 2; ++r) {
            int lo = (w * 2 + r) * 1024 + lane * 16;   // byte offset in tile
            int row = lo >> 7, cp = (lo >> 4) & 7, c = (cp - row) & 7;
            gload_lds16(Kp + ((size_t)(kt * 64 + row) * 64 + c * 8) * 2,
                        (char*)Ks[buf] + lo);
            gload_lds16(Vp + ((size_t)row * TKn + kt * 64 + c * 8) * 2,
                        (char*)Vts[buf] + lo);
        }
    };

    stage(0, 0);
    for (int kt = 0; kt < nkt; ++kt) {
        const int buf = kt & 1;
        __syncthreads();                    // drains this tile's loads (covered)
        if (kt + 1 < nkt) stage(kt + 1, buf ^ 1);

        // --- S^T = K * Q^T (A = K frag: m = key, B = Q frag: n = q) ---
        const short* KsB = Ks[buf];
        f32x4 s[4];
#pragma unroll
        for (int ch = 0; ch < 4; ++ch) {
            int row = ch * 16 + rl;
            bf16x8 k0 = *(const bf16x8*)(KsB + row * 64 + ((rg + row) & 7) * 8);
            bf16x8 k1 = *(const bf16x8*)(KsB + row * 64 + ((rg + 4 + row) & 7) * 8);
            f32x4 z = {};
            z = mfma16(k0, qf0, z);
            z = mfma16(k1, qf1, z);
            s[ch] = z;
        }
        // --- exp + causal mask (last tile only) + P^T pack to LDS ---
        const bool domask = CAUSAL && (kt == nkt - 1);
#pragma unroll
        for (int ch = 0; ch < 4; ++ch) {
            float p[4];
#pragma unroll
            for (int r = 0; r < 4; ++r) {
                float e = __expf(s[ch][r]);
                if (domask) {
                    int key = kt * 64 + ch * 16 + rg * 4 + r;
                    if (key > qrow) e = 0.0f;
                }
                p[r] = e;
            }
            unsigned d0 = (__builtin_bit_cast(unsigned, p[1]) & 0xFFFF0000u) |
                          (__builtin_bit_cast(unsigned, p[0]) >> 16);
            unsigned d1 = (__builtin_bit_cast(unsigned, p[3]) & 0xFFFF0000u) |
                          (__builtin_bit_cast(unsigned, p[2]) >> 16);
            uint2 dv; dv.x = d0; dv.y = d1;
            *(uint2*)(Pw + rl * 72 + ch * 16 + rg * 4) = dv;
        }
        // --- P A-frags + row-sum + PV ---
        bf16x8 pa0 = *(const bf16x8*)(Pw + rl * 72 + rg * 8);
        bf16x8 pa1 = *(const bf16x8*)(Pw + rl * 72 + 32 + rg * 8);
        lacc = mfma16(pa0, onesf, lacc);
        lacc = mfma16(pa1, onesf, lacc);
        const short* VsB = Vts[buf];
#pragma unroll
        for (int j = 0; j < 4; ++j) {
            int row = j * 16 + rl;
            bf16x8 v0 = *(const bf16x8*)(VsB + row * 64 + ((rg + row) & 7) * 8);
            bf16x8 v1 = *(const bf16x8*)(VsB + row * 64 + ((rg + 4 + row) & 7) * 8);
            o[j] = mfma16(pa0, v0, o[j]);
            o[j] = mfma16(pa1, v1, o[j]);
        }
    }

    float inv[4];
#pragma unroll
    for (int r = 0; r < 4; r++) inv[r] = 1.0f / lacc[r];
#pragma unroll
    for (int j = 0; j < 4; j++) {
#pragma unroll
        for (int r = 0; r < 4; r++) {
            int row = q0 + w * 16 + rg * 4 + r;
            int col = h * 64 + j * 16 + rl;
            Out[((size_t)b * 1024 + row) * 1024 + col] = f2bfs(o[j][r] * inv[r]);
        }
    }
}

// ---------------------------------------------------------------------------
// Fused residual add (+ optional second partial R2) + LayerNorm over C=1024.
// Writes f32 (+optional bf16).
// ---------------------------------------------------------------------------
__global__ __launch_bounds__(256) void ln_fused(const float* __restrict__ X,
                                                const float* __restrict__ R,
                                                const float* __restrict__ R2,
                                                const float* __restrict__ gam,
                                                const float* __restrict__ bet,
                                                float* __restrict__ Yf,
                                                short* __restrict__ Yb) {
    const int row = blockIdx.x, tid = threadIdx.x;
    const int lane = tid & 63, w = tid >> 6;
    float4 xv = ((const float4*)(X + (size_t)row * 1024))[tid];
    float4 rv = ((const float4*)(R + (size_t)row * 1024))[tid];
    float v0 = xv.x + rv.x, v1 = xv.y + rv.y, v2 = xv.z + rv.z, v3 = xv.w + rv.w;
    if (R2) {
        float4 r2 = ((const float4*)(R2 + (size_t)row * 1024))[tid];
        v0 += r2.x; v1 += r2.y; v2 += r2.z; v3 += r2.w;
    }
    float s = v0 + v1 + v2 + v3;
    float ss = v0 * v0 + v1 * v1 + v2 * v2 + v3 * v3;
#pragma unroll
    for (int off = 1; off < 64; off <<= 1) {
        s += __shfl_xor(s, off);
        ss += __shfl_xor(ss, off);
    }
    __shared__ float sred[4], ssred[4];
    if (lane == 0) { sred[w] = s; ssred[w] = ss; }
    __syncthreads();
    s = sred[0] + sred[1] + sred[2] + sred[3];
    ss = ssred[0] + ssred[1] + ssred[2] + ssred[3];
    float mu = s * (1.0f / 1024.0f);
    float var = ss * (1.0f / 1024.0f) - mu * mu;
    float rsq = rsqrtf(var + 1e-12f);
    float4 gv = ((const float4*)gam)[tid];
    float4 bv = ((const float4*)bet)[tid];
    float y0 = (v0 - mu) * rsq * gv.x + bv.x;
    float y1 = (v1 - mu) * rsq * gv.y + bv.y;
    float y2 = (v2 - mu) * rsq * gv.z + bv.z;
    float y3 = (v3 - mu) * rsq * gv.w + bv.w;
    float4 yo = {y0, y1, y2, y3};
    ((float4*)(Yf + (size_t)row * 1024))[tid] = yo;
    if (Yb) {
        short4 ob;
        ob.x = f2bfs(y0); ob.y = f2bfs(y1); ob.z = f2bfs(y2); ob.w = f2bfs(y3);
        ((short4*)(Yb + (size_t)row * 1024))[tid] = ob;
    }
}

// ---------------------------------------------------------------------------
extern "C" void kernel_launch(void* const* d_in, const int* in_sizes, int n_in,
                              void* d_out, int out_size, void* d_ws, size_t ws_size,
                              hipStream_t stream) {
    const float* src = (const float*)d_in[0];
    const float* dst = (const float*)d_in[1];
    // d_in[2]=src_mask (all valid), d_in[3]=dst_mask (causal) — structurally fixed
    const float* sa_wq = (const float*)d_in[4];
    const float* sa_wk = (const float*)d_in[5];
    const float* sa_wv = (const float*)d_in[6];
    const float* sa_wo = (const float*)d_in[7];
    const float* sa_bq = (const float*)d_in[8];
    const float* sa_bk = (const float*)d_in[9];
    const float* sa_bv = (const float*)d_in[10];
    const float* sa_bo = (const float*)d_in[11];
    const float* ca_wq = (const float*)d_in[12];
    const float* ca_wk = (const float*)d_in[13];
    const float* ca_wv = (const float*)d_in[14];
    const float* ca_wo = (const float*)d_in[15];
    const float* ca_bq = (const float*)d_in[16];
    const float* ca_bk = (const float*)d_in[17];
    const float* ca_bv = (const float*)d_in[18];
    const float* ca_bo = (const float*)d_in[19];
    const float* ffn_w1 = (const float*)d_in[20];
    const float* ffn_b1 = (const float*)d_in[21];
    const float* ffn_w2 = (const float*)d_in[22];
    const float* ffn_b2 = (const float*)d_in[23];
    const float* ln1g = (const float*)d_in[24];
    const float* ln1b = (const float*)d_in[25];
    const float* ln2g = (const float*)d_in[26];
    const float* ln2b = (const float*)d_in[27];
    const float* ln3g = (const float*)d_in[28];
    const float* ln3b = (const float*)d_in[29];

    char* ws = (char*)d_ws;
    size_t off = 0;
    auto alloc = [&](size_t n) { size_t o = off; off = (off + n + 255) & ~(size_t)255; return o; };

    const size_t szW = (size_t)1024 * 1024 * 2;      // 2 MB bf16 1024x1024
    short* wT = (short*)(ws + alloc(8 * szW));       // 8 transposed attn weights
    short* w1T = (short*)(ws + alloc((size_t)4096 * 1024 * 2));
    short* w2T = (short*)(ws + alloc((size_t)1024 * 4096 * 2));
    const size_t szAct2 = (size_t)4096 * 1024 * 2;   // 8 MB bf16 activations
    const size_t szAct4 = (size_t)4096 * 1024 * 4;   // 16 MB f32 activations
    short* dstb = (short*)(ws + alloc(szAct2));
    short* srcb = (short*)(ws + alloc(szAct2));
    short* Qh = (short*)(ws + alloc(szAct2));
    short* Kh = (short*)(ws + alloc(szAct2));
    short* VTh = (short*)(ws + alloc(szAct2));
    short* attnb = (short*)(ws + alloc(szAct2));
    float* tmp = (float*)(ws + alloc(szAct4));       // single f32 GEMM output
    float* y1f = (float*)(ws + alloc(szAct4));
    short* y1b = (short*)(ws + alloc(szAct2));
    float* y2f = (float*)(ws + alloc(szAct4));
    short* y2b = (short*)(ws + alloc(szAct2));
    short* ffnh = (short*)(ws + alloc((size_t)4096 * 4096 * 2));

    // transposed-weight views (order matches WPtrs below)
    short* sa_wqkvT = wT;                 // rows 0..3071 = wq^T, wk^T, wv^T
    short* sa_woT = wT + 3 * (size_t)1048576;
    short* ca_wqT = wT + 4 * (size_t)1048576;
    short* ca_wkvT = wT + 5 * (size_t)1048576;  // rows 0..2047 = wk^T, wv^T
    short* ca_woT = wT + 7 * (size_t)1048576;

    dim3 blk(256);

    // weight prep
    WPtrs wp = {{sa_wq, sa_wk, sa_wv, sa_wo, ca_wq, ca_wk, ca_wv, ca_wo}};
    wtrans8<<<dim3(16, 16, 8), blk, 0, stream>>>(wp, wT);
    wtrans<<<dim3(64, 16), blk, 0, stream>>>(ffn_w1, w1T, 1024, 4096);
    wtrans<<<dim3(16, 64), blk, 0, stream>>>(ffn_w2, w2T, 4096, 1024);
    conv_bf16<<<2048, blk, 0, stream>>>(dst, dstb, 524288);
    conv_bf16<<<2048, blk, 0, stream>>>(src, srcb, 524288);

    // ---- self-attention ----
    gemm_bt<128, 128, 32, 1, 0><<<dim3(24, 32), blk, 0, stream>>>(
        dstb, sa_wqkvT, sa_bq, sa_bk, sa_bv, Qh, Kh, VTh, 4096, 3072, 1024, 1024);
    attn4<true><<<dim3(16, 64), blk, 0, stream>>>(Qh, Kh, VTh, attnb, 1024);
    gemm_bt<64, 64, 64, 0, 1><<<dim3(16, 64), blk, 0, stream>>>(
        attnb, sa_woT, sa_bo, nullptr, nullptr, tmp, nullptr, nullptr, 4096, 1024, 1024, 1024);
    ln_fused<<<4096, blk, 0, stream>>>(dst, tmp, nullptr, ln1g, ln1b, y1f, y1b);

    // ---- cross-attention ----
    gemm_bt<64, 64, 64, 1, 1><<<dim3(16, 64), blk, 0, stream>>>(
        y1b, ca_wqT, ca_bq, nullptr, nullptr, Qh, nullptr, nullptr, 4096, 1024, 1024, 1024);
    gemm_bt<128, 128, 32, 3, 0><<<dim3(16, 32), blk, 0, stream>>>(
        srcb, ca_wkvT, ca_bk, ca_bv, nullptr, Kh, VTh, nullptr, 4096, 2048, 1024, 1024);
    attn4<false><<<dim3(16, 64), blk, 0, stream>>>(Qh, Kh, VTh, attnb, 1024);
    gemm_bt<64, 64, 64, 0, 1><<<dim3(16, 64), blk, 0, stream>>>(
        attnb, ca_woT, ca_bo, nullptr, nullptr, tmp, nullptr, nullptr, 4096, 1024, 1024, 1024);
    ln_fused<<<4096, blk, 0, stream>>>(y1f, tmp, nullptr, ln2g, ln2b, y2f, y2b);

    // ---- FFN ----
    gemm_bt<128, 128, 32, 2, 0><<<dim3(32, 32), blk, 0, stream>>>(
        y2b, w1T, ffn_b1, nullptr, nullptr, ffnh, nullptr, nullptr, 4096, 4096, 1024, 1024);
    gemm_bt<64, 64, 64, 0, 1><<<dim3(16, 64), blk, 0, stream>>>(
        ffnh, w2T, ffn_b2, nullptr, nullptr, tmp, nullptr, nullptr, 4096, 1024, 4096, 4096);
    ln_fused<<<4096, blk, 0, stream>>>(y2f, tmp, nullptr, ln3g, ln3b, (float*)d_out, nullptr);

    (void)in_sizes; (void)n_in; (void)out_size; (void)ws_size;
}